// Round 2
// baseline (1555.435 us; speedup 1.0000x reference)
//
#include <hip/hip_runtime.h>
#include <hip/hip_bf16.h>
#include <math.h>

#define NN     10000
#define EE     320000
#define IN_CH  739
#define CC     64
#define GG     64
#define NLAYER 9

__device__ __forceinline__ float eluf(float x) { return x > 0.f ? x : expm1f(x); }
__device__ __forceinline__ float softplusf(float x) {
    return fmaxf(x, 0.f) + log1pf(expf(-fabsf(x)));
}
__device__ __forceinline__ float wave_sum(float v) {
#pragma unroll
    for (int off = 32; off > 0; off >>= 1) v += __shfl_xor(v, off, 64);
    return v;
}

// ---------------------------------------------------------------------------
// InitFeat: h = elu(x@w0+b0)@w1+b1 ; UpdateZ k=0: z = h * (hop_att0·elu(h)+b)
// One wave per node row. 4 rows per 256-thread block. 10000 % 4 == 0.
// ---------------------------------------------------------------------------
__global__ __launch_bounds__(256) void k_init(
    const float* __restrict__ x,
    const float* __restrict__ w0,
    const float* __restrict__ b0,
    const float* __restrict__ w1,
    const float* __restrict__ b1,
    const float* __restrict__ hop_att0,
    const float* __restrict__ hop_bias0,
    float* __restrict__ xout, float* __restrict__ zout)
{
    __shared__ float sx[4][IN_CH];
    __shared__ float sh[4][CC];
    const int r = threadIdx.x >> 6;     // wave within block = local row
    const int c = threadIdx.x & 63;     // lane = output channel
    const int row = (blockIdx.x << 2) + r;

    for (int k = c; k < IN_CH; k += 64) sx[r][k] = x[row * IN_CH + k];
    __syncthreads();

    float acc = 0.f;
#pragma unroll 4
    for (int k = 0; k < IN_CH; ++k)
        acc = fmaf(sx[r][k], w0[k * CC + c], acc);
    acc += b0[c];
    sh[r][c] = eluf(acc);
    __syncthreads();

    float acc2 = 0.f;
#pragma unroll 8
    for (int k = 0; k < CC; ++k)
        acc2 = fmaf(sh[r][k], w1[k * CC + c], acc2);
    acc2 += b1[c];

    // UpdateZ k=0
    float g = hop_att0[c] * eluf(acc2);
    float attn = wave_sum(g) + hop_bias0[0];
    xout[row * CC + c] = acc2;
    zout[row * CC + c] = acc2 * attn;
}

// ---------------------------------------------------------------------------
// Per-edge attention: a_e = softplus(conv_att · elu(scale*(z[s]+z[d]))) + 1e-6
// Thread per edge; float4 gathers; atomicAdd degree sum at dst.
// ---------------------------------------------------------------------------
__global__ __launch_bounds__(256) void k_edge_att(
    const int* __restrict__ ei, const float* __restrict__ z,
    const float* __restrict__ conv_att, float scale,
    float* __restrict__ a, float* __restrict__ adj)
{
    __shared__ float sca[CC];
    if (threadIdx.x < CC) sca[threadIdx.x] = conv_att[threadIdx.x];
    __syncthreads();

    const int e = blockIdx.x * 256 + threadIdx.x;   // grid sized exactly to EE
    const int s = ei[e];
    const int d = ei[EE + e];
    const float4* zs = (const float4*)(z + s * CC);
    const float4* zd = (const float4*)(z + d * CC);
    float acc = 0.f;
#pragma unroll
    for (int j = 0; j < CC / 4; ++j) {
        float4 av = zs[j];
        float4 bv = zd[j];
        acc = fmaf(sca[4 * j + 0], eluf((av.x + bv.x) * scale), acc);
        acc = fmaf(sca[4 * j + 1], eluf((av.y + bv.y) * scale), acc);
        acc = fmaf(sca[4 * j + 2], eluf((av.z + bv.z) * scale), acc);
        acc = fmaf(sca[4 * j + 3], eluf((av.w + bv.w) * scale), acc);
    }
    const float ae = softplusf(acc) + 1e-6f;
    a[e] = ae;
    atomicAdd(&adj[d], ae);
}

// ---------------------------------------------------------------------------
// Messages: x_new[d] += x[s] * (a_e * rsqrt(adj[s]) * rsqrt(adj[d]))
// One wave per edge, lane = channel. Coalesced 256B gather + 64 atomics.
// ---------------------------------------------------------------------------
__global__ __launch_bounds__(256) void k_msg(
    const int* __restrict__ ei, const float* __restrict__ a,
    const float* __restrict__ adj, const float* __restrict__ x,
    float* __restrict__ xn)
{
    const int idx = blockIdx.x * 256 + threadIdx.x;  // EE*64 threads exactly
    const int e = idx >> 6;
    const int c = idx & 63;
    const int s = ei[e];
    const int d = ei[EE + e];
    const float na = a[e] * rsqrtf(fmaxf(adj[s], 1e-32f))
                          * rsqrtf(fmaxf(adj[d], 1e-32f));
    atomicAdd(&xn[d * CC + c], x[s * CC + c] * na);
}

// ---------------------------------------------------------------------------
// UpdateZ k>=1: attn = hop_att·elu([x_new, z*scale]) + bias ; z += x_new*attn
// One wave per node. Also zeroes the retired x buffer and adj for next layer.
// ---------------------------------------------------------------------------
__global__ __launch_bounds__(256) void k_update_z(
    const float* __restrict__ xn, float* __restrict__ z,
    const float* __restrict__ hop_att,
    const float* __restrict__ hop_bias, float scale,
    float* __restrict__ xold_zero, float* __restrict__ adj_zero)
{
    const int idx = blockIdx.x * 256 + threadIdx.x;  // NN*64 threads exactly
    const int n = idx >> 6;
    const int c = idx & 63;
    const float xv = xn[idx];
    const float zv = z[idx];
    float g = hop_att[c] * eluf(xv) + hop_att[CC + c] * eluf(zv * scale);
    const float attn = wave_sum(g) + hop_bias[0];
    z[idx] = zv + xv * attn;
    xold_zero[idx] = 0.f;
    if (c == 0) adj_zero[n] = 0.f;
}

// ---------------------------------------------------------------------------
// Readout pool: pool[batch[n]] += elu(z[n]) ; cnt[batch[n]] += 1
// ---------------------------------------------------------------------------
__global__ __launch_bounds__(256) void k_pool(
    const float* __restrict__ z, const int* __restrict__ batch,
    float* __restrict__ pool, float* __restrict__ cnt)
{
    const int idx = blockIdx.x * 256 + threadIdx.x;  // NN*64 threads
    const int n = idx >> 6;
    const int c = idx & 63;
    const float v = eluf(z[idx]);
    const int b = batch[n];
    atomicAdd(&pool[b * CC + c], v);
    if (c == 0) atomicAdd(&cnt[b], 1.0f);
}

__global__ __launch_bounds__(64) void k_head(
    const float* __restrict__ pool, const float* __restrict__ cnt,
    const float* __restrict__ w_head,
    const float* __restrict__ b_head,
    float* __restrict__ out)
{
    const int g = threadIdx.x;
    float acc = 0.f;
#pragma unroll 8
    for (int c = 0; c < CC; ++c)
        acc = fmaf(pool[g * CC + c], w_head[c], acc);
    const float cn = fmaxf(cnt[g], 1.0f);
    out[g] = acc / cn + b_head[0];
}

extern "C" void kernel_launch(void* const* d_in, const int* in_sizes, int n_in,
                              void* d_out, int out_size, void* d_ws, size_t ws_size,
                              hipStream_t stream) {
    const float* x        = (const float*)d_in[0];
    const int*   ei       = (const int*)d_in[1];
    const int*   batch    = (const int*)d_in[2];
    const float* w0       = (const float*)d_in[3];
    const float* b0       = (const float*)d_in[4];
    const float* w1       = (const float*)d_in[5];
    const float* b1       = (const float*)d_in[6];
    const float* conv_att = (const float*)d_in[7];
    const float* hop_att0 = (const float*)d_in[8];
    const float* hop_bias0= (const float*)d_in[9];
    const float* hop_att  = (const float*)d_in[10];
    const float* hop_bias = (const float*)d_in[11];
    const float* w_head   = (const float*)d_in[12];
    const float* b_head   = (const float*)d_in[13];
    float* out = (float*)d_out;

    // Workspace layout (fp32). bufB and adj are contiguous -> single memset.
    float* bufA = (float*)d_ws;          // NN*CC
    float* bufB = bufA + NN * CC;        // NN*CC
    float* adj  = bufB + NN * CC;        // NN
    float* zbuf = adj + NN;              // NN*CC
    float* abuf = zbuf + NN * CC;        // EE
    float* pool = abuf + EE;             // GG*CC
    float* cnt  = pool + GG * CC;        // GG

    hipMemsetAsync(bufB, 0, (size_t)(NN * CC + NN) * sizeof(float), stream);
    hipMemsetAsync(pool, 0, (size_t)(GG * CC + GG) * sizeof(float), stream);

    k_init<<<NN / 4, 256, 0, stream>>>(x, w0, b0, w1, b1, hop_att0, hop_bias0,
                                       bufA, zbuf);

    float* xcur = bufA;
    float* xnext = bufB;
    for (int i = 0; i < NLAYER; ++i) {
        const int k = i + 1;
        const float scale = (float)log(1.0 / (double)k + 1.0 + 1e-6);
        k_edge_att<<<EE / 256, 256, 0, stream>>>(ei, zbuf, conv_att + i * CC,
                                                 scale, abuf, adj);
        k_msg<<<EE * CC / 256, 256, 0, stream>>>(ei, abuf, adj, xcur, xnext);
        k_update_z<<<NN * CC / 256, 256, 0, stream>>>(
            xnext, zbuf, hop_att + i * 2 * CC, hop_bias + i, scale,
            xcur /* zero for next layer */, adj /* zero for next layer */);
        float* t = xcur; xcur = xnext; xnext = t;
    }

    k_pool<<<NN * CC / 256, 256, 0, stream>>>(zbuf, batch, pool, cnt);
    k_head<<<1, 64, 0, stream>>>(pool, cnt, w_head, b_head, out);
}

// Round 3
// 831.213 us; speedup vs baseline: 1.8713x; 1.8713x over previous
//
#include <hip/hip_runtime.h>
#include <hip/hip_bf16.h>
#include <math.h>

#define NN     10000
#define EE     320000
#define IN_CH  739
#define CC     64
#define GG     64
#define NLAYER 9

__device__ __forceinline__ float eluf(float x) { return x > 0.f ? x : expm1f(x); }
__device__ __forceinline__ float softplusf(float x) {
    return fmaxf(x, 0.f) + log1pf(expf(-fabsf(x)));
}
__device__ __forceinline__ float wave_sum(float v) {
#pragma unroll
    for (int off = 32; off > 0; off >>= 1) v += __shfl_xor(v, off, 64);
    return v;
}

// ---------------------------------------------------------------------------
// InitFeat + UpdateZ(k=0). Block = 256 thr = 4 waves; block handles 16 rows;
// each wave computes 4 rows (4 independent fma chains share each w0 load).
// ---------------------------------------------------------------------------
__global__ __launch_bounds__(256) void k_init(
    const float* __restrict__ x,
    const float* __restrict__ w0, const float* __restrict__ b0,
    const float* __restrict__ w1, const float* __restrict__ b1,
    const float* __restrict__ hop_att0, const float* __restrict__ hop_bias0,
    float* __restrict__ xout, float* __restrict__ zout)
{
    __shared__ float sx[16 * IN_CH];
    __shared__ float sh[16 * CC];
    const int tid = threadIdx.x;
    const int w = tid >> 6;            // wave id: rows 4w..4w+3
    const int c = tid & 63;            // lane = output channel
    const int row0 = blockIdx.x * 16;  // 625 blocks * 16 = 10000

    // stage 16 rows of x (contiguous 16*739 floats), float4-coalesced
    {
        const float4* xin = (const float4*)(x + (size_t)row0 * IN_CH);
        float4* s4 = (float4*)sx;
        for (int i = tid; i < 16 * IN_CH / 4; i += 256) s4[i] = xin[i];
    }
    __syncthreads();

    float acc[4];
#pragma unroll
    for (int j = 0; j < 4; ++j) acc[j] = b0[c];
#pragma unroll 4
    for (int k = 0; k < IN_CH; ++k) {
        const float wv = w0[k * CC + c];
#pragma unroll
        for (int j = 0; j < 4; ++j)
            acc[j] = fmaf(sx[(4 * w + j) * IN_CH + k], wv, acc[j]);
    }
#pragma unroll
    for (int j = 0; j < 4; ++j) sh[(4 * w + j) * CC + c] = eluf(acc[j]);
    __syncthreads();

    float acc2[4];
#pragma unroll
    for (int j = 0; j < 4; ++j) acc2[j] = b1[c];
#pragma unroll 8
    for (int k = 0; k < CC; ++k) {
        const float wv = w1[k * CC + c];
#pragma unroll
        for (int j = 0; j < 4; ++j)
            acc2[j] = fmaf(sh[(4 * w + j) * CC + k], wv, acc2[j]);
    }

    const float ha = hop_att0[c];
    const float hb = hop_bias0[0];
#pragma unroll
    for (int j = 0; j < 4; ++j) {
        const float attn = wave_sum(ha * eluf(acc2[j])) + hb;
        const int row = row0 + 4 * w + j;
        xout[row * CC + c] = acc2[j];
        zout[row * CC + c] = acc2[j] * attn;
    }
}

// ---------------------------------------------------------------------------
// CSR build (dst-sorted): histogram -> exclusive scan -> scatter
// ---------------------------------------------------------------------------
__global__ __launch_bounds__(256) void k_hist(const int* __restrict__ ei,
                                              int* __restrict__ deg)
{
    const int e = blockIdx.x * 256 + threadIdx.x;   // grid == EE/256
    atomicAdd(&deg[ei[EE + e]], 1);
}

__global__ __launch_bounds__(256) void k_scan(const int* __restrict__ deg,
                                              int* __restrict__ offs)
{
    __shared__ int part[256];
    const int tid = threadIdx.x;
    const int start = tid * 40;
    const int end = start + 40 < NN ? start + 40 : NN;
    int sum = 0;
    for (int i = start; i < end; ++i) sum += deg[i];
    part[tid] = sum;
    __syncthreads();
    if (tid == 0) {
        int run = 0;
        for (int i = 0; i < 256; ++i) { int t = part[i]; part[i] = run; run += t; }
    }
    __syncthreads();
    int run = part[tid];
    for (int i = start; i < end; ++i) { offs[i] = run; run += deg[i]; }
}

__global__ __launch_bounds__(256) void k_scatter(
    const int* __restrict__ ei, const int* __restrict__ offs,
    int* __restrict__ cursor, int* __restrict__ csr_src,
    int* __restrict__ edge_pos)
{
    const int e = blockIdx.x * 256 + threadIdx.x;
    const int d = ei[EE + e];
    const int pos = offs[d] + atomicAdd(&cursor[d], 1);
    csr_src[pos] = ei[e];
    edge_pos[e] = pos;
}

// ---------------------------------------------------------------------------
// Edge attention: 16 lanes per edge (4 edges/wave, 16 edges/block).
// a_e = softplus(conv_att . elu(scale*(z[s]+z[d]))) + 1e-6, written in CSR
// order; scalar atomicAdd of a_e into adj[d].
// ---------------------------------------------------------------------------
__global__ __launch_bounds__(256) void k_edge_att(
    const int* __restrict__ ei, const int* __restrict__ edge_pos,
    const float* __restrict__ z, const float* __restrict__ conv_att,
    float scale, float* __restrict__ a_csr, float* __restrict__ adj)
{
    __shared__ float sca[CC];
    if (threadIdx.x < CC) sca[threadIdx.x] = conv_att[threadIdx.x];
    __syncthreads();

    const int e = blockIdx.x * 16 + (threadIdx.x >> 4);   // grid == EE/16
    const int l = threadIdx.x & 15;
    const int s = ei[e];
    const int d = ei[EE + e];
    const float4 zs = *(const float4*)(z + s * CC + l * 4);
    const float4 zd = *(const float4*)(z + d * CC + l * 4);
    float p = sca[4 * l + 0] * eluf((zs.x + zd.x) * scale);
    p = fmaf(sca[4 * l + 1], eluf((zs.y + zd.y) * scale), p);
    p = fmaf(sca[4 * l + 2], eluf((zs.z + zd.z) * scale), p);
    p = fmaf(sca[4 * l + 3], eluf((zs.w + zd.w) * scale), p);
#pragma unroll
    for (int off = 8; off > 0; off >>= 1) p += __shfl_xor(p, off, 64);
    if (l == 0) {
        const float ae = softplusf(p) + 1e-6f;
        a_csr[edge_pos[e]] = ae;
        atomicAdd(&adj[d], ae);
    }
}

// ---------------------------------------------------------------------------
// Fused message gather + UpdateZ. One wave per dst node, lane = channel.
// Edge metadata loaded lane-parallel (coalesced) then shfl-broadcast.
// No atomics, no zeroed buffers.
// ---------------------------------------------------------------------------
__global__ __launch_bounds__(256) void k_msg_fused(
    const int* __restrict__ offs, const int* __restrict__ deg,
    const int* __restrict__ csr_src, const float* __restrict__ a_csr,
    const float* __restrict__ adj, const float* __restrict__ x,
    float* __restrict__ xn, float* __restrict__ z,
    const float* __restrict__ hop_att, const float* __restrict__ hop_bias,
    float scale)
{
    const int n = blockIdx.x * 4 + (threadIdx.x >> 6);   // grid == NN/4
    const int c = threadIdx.x & 63;
    const int start = offs[n];
    const int len = deg[n];
    const float invd = rsqrtf(fmaxf(adj[n], 1e-32f));

    float acc = 0.f;
    for (int base = 0; base < len; base += 64) {
        const int cnt = (len - base) < 64 ? (len - base) : 64;
        int s_l = 0; float na_l = 0.f;
        if (c < cnt) {
            s_l = csr_src[start + base + c];
            na_l = a_csr[start + base + c] *
                   rsqrtf(fmaxf(adj[s_l], 1e-32f)) * invd;
        }
        for (int j = 0; j < cnt; ++j) {
            const int s = __shfl(s_l, j, 64);
            const float na = __shfl(na_l, j, 64);
            acc = fmaf(x[s * CC + c], na, acc);
        }
    }

    // UpdateZ (k >= 1)
    const float zv = z[n * CC + c];
    float g = hop_att[c] * eluf(acc) + hop_att[CC + c] * eluf(zv * scale);
    const float attn = wave_sum(g) + hop_bias[0];
    z[n * CC + c] = zv + acc * attn;
    xn[n * CC + c] = acc;
}

// ---------------------------------------------------------------------------
// Readout
// ---------------------------------------------------------------------------
__global__ __launch_bounds__(256) void k_pool(
    const float* __restrict__ z, const int* __restrict__ batch,
    float* __restrict__ pool, float* __restrict__ cnt)
{
    const int idx = blockIdx.x * 256 + threadIdx.x;  // NN*64 threads
    const int n = idx >> 6;
    const int c = idx & 63;
    const float v = eluf(z[idx]);
    const int b = batch[n];
    atomicAdd(&pool[b * CC + c], v);
    if (c == 0) atomicAdd(&cnt[b], 1.0f);
}

__global__ __launch_bounds__(64) void k_head(
    const float* __restrict__ pool, const float* __restrict__ cnt,
    const float* __restrict__ w_head, const float* __restrict__ b_head,
    float* __restrict__ out)
{
    const int g = threadIdx.x;
    float acc = 0.f;
#pragma unroll 8
    for (int c = 0; c < CC; ++c)
        acc = fmaf(pool[g * CC + c], w_head[c], acc);
    out[g] = acc / fmaxf(cnt[g], 1.0f) + b_head[0];
}

extern "C" void kernel_launch(void* const* d_in, const int* in_sizes, int n_in,
                              void* d_out, int out_size, void* d_ws, size_t ws_size,
                              hipStream_t stream) {
    const float* x        = (const float*)d_in[0];
    const int*   ei       = (const int*)d_in[1];
    const int*   batch    = (const int*)d_in[2];
    const float* w0       = (const float*)d_in[3];
    const float* b0       = (const float*)d_in[4];
    const float* w1       = (const float*)d_in[5];
    const float* b1       = (const float*)d_in[6];
    const float* conv_att = (const float*)d_in[7];
    const float* hop_att0 = (const float*)d_in[8];
    const float* hop_bias0= (const float*)d_in[9];
    const float* hop_att  = (const float*)d_in[10];
    const float* hop_bias = (const float*)d_in[11];
    const float* w_head   = (const float*)d_in[12];
    const float* b_head   = (const float*)d_in[13];
    float* out = (float*)d_out;

    // ---- workspace layout ----
    float* xA    = (float*)d_ws;                 // NN*CC
    float* xB    = xA + NN * CC;                 // NN*CC
    float* zbuf  = xB + NN * CC;                 // NN*CC
    float* a_csr = zbuf + NN * CC;               // EE
    // zero block starts here:
    float* adj9  = a_csr + EE;                   // NLAYER*NN
    float* pool  = adj9 + NLAYER * NN;           // GG*CC
    float* cnt   = pool + GG * CC;               // GG
    int*   deg   = (int*)(cnt + GG);             // NN
    int*   cursor= deg + NN;                     // NN
    // end zero block
    int*   offs  = cursor + NN;                  // NN
    int*   csr_src = offs + NN;                  // EE
    int*   edge_pos = csr_src + EE;              // EE

    const size_t zero_bytes =
        (size_t)(NLAYER * NN + GG * CC + GG + NN + NN) * 4;
    hipMemsetAsync(adj9, 0, zero_bytes, stream);

    k_init<<<NN / 16, 256, 0, stream>>>(x, w0, b0, w1, b1, hop_att0, hop_bias0,
                                        xA, zbuf);
    k_hist<<<EE / 256, 256, 0, stream>>>(ei, deg);
    k_scan<<<1, 256, 0, stream>>>(deg, offs);
    k_scatter<<<EE / 256, 256, 0, stream>>>(ei, offs, cursor, csr_src, edge_pos);

    float* xcur = xA;
    float* xnext = xB;
    for (int i = 0; i < NLAYER; ++i) {
        const int k = i + 1;
        const float scale = (float)log(1.0 / (double)k + 1.0 + 1e-6);
        float* adj = adj9 + i * NN;
        k_edge_att<<<EE / 16, 256, 0, stream>>>(ei, edge_pos, zbuf,
                                                conv_att + i * CC, scale,
                                                a_csr, adj);
        k_msg_fused<<<NN / 4, 256, 0, stream>>>(offs, deg, csr_src, a_csr, adj,
                                                xcur, xnext, zbuf,
                                                hop_att + i * 2 * CC,
                                                hop_bias + i, scale);
        float* t = xcur; xcur = xnext; xnext = t;
    }

    k_pool<<<NN * CC / 256, 256, 0, stream>>>(zbuf, batch, pool, cnt);
    k_head<<<1, 64, 0, stream>>>(pool, cnt, w_head, b_head, out);
}

// Round 4
// 694.669 us; speedup vs baseline: 2.2391x; 1.1966x over previous
//
#include <hip/hip_runtime.h>
#include <hip/hip_bf16.h>
#include <math.h>

#define NN     10000
#define EE     320000
#define IN_CH  739
#define CC     64
#define GG     64
#define NLAYER 9
#define KTILES 12   // ceil(739/64)

__device__ __forceinline__ float eluf(float x) { return x > 0.f ? x : expm1f(x); }
__device__ __forceinline__ float softplusf(float x) {
    return fmaxf(x, 0.f) + log1pf(expf(-fabsf(x)));
}
__device__ __forceinline__ float wave_sum(float v) {
#pragma unroll
    for (int off = 32; off > 0; off >>= 1) v += __shfl_xor(v, off, 64);
    return v;
}

// ---------------------------------------------------------------------------
// InitFeat + UpdateZ(k=0) as a register-tiled GEMM.
// Block: 256 thr, 64 rows x 64 cols of h. Thread: 4 rows x 4 cols.
// K-tiles of 64 staged to LDS (xs stride 68: 16B-aligned rows, bank-spread).
// Global->reg prefetch of tile t+1 overlaps compute of tile t.
// GEMM2 (elu(h)@w1+b1) and the k=0 hop-attention fused via LDS reuse.
// ---------------------------------------------------------------------------
__global__ __launch_bounds__(256) void k_init(
    const float* __restrict__ x,
    const float* __restrict__ w0, const float* __restrict__ b0,
    const float* __restrict__ w1, const float* __restrict__ b1,
    const float* __restrict__ hop_att0, const float* __restrict__ hop_bias0,
    float* __restrict__ xout, float* __restrict__ zout)
{
    __shared__ float xs[64 * 68];   // [row][k], stride 68
    __shared__ float ws[64 * 64];   // [k][col], stride 64
    const int tid = threadIdx.x;
    const int cg = tid & 15;        // col group: cols cg*4 .. cg*4+3
    const int rg = tid >> 4;        // row group: rows rg*4 .. rg*4+3
    const int R0 = blockIdx.x * 64; // 157 blocks, last partial

    const int sk = tid & 63;        // staging: k-in-tile (x) / col (w)
    const int sr = tid >> 6;        // staging: row base (steps of 4)

    float xr[16], wr[16];
    float acc[4][4];
    const float4 b0v = *(const float4*)&b0[cg * 4];
#pragma unroll
    for (int j = 0; j < 4; ++j) {
        acc[j][0] = b0v.x; acc[j][1] = b0v.y;
        acc[j][2] = b0v.z; acc[j][3] = b0v.w;
    }

    // prefetch tile 0
#pragma unroll
    for (int i = 0; i < 16; ++i) {
        const int r = sr + 4 * i;
        const int gr = R0 + r;
        xr[i] = (gr < NN && sk < IN_CH) ? x[(size_t)gr * IN_CH + sk] : 0.f;
        wr[i] = (r < IN_CH) ? w0[r * CC + sk] : 0.f;
    }

    for (int t = 0; t < KTILES; ++t) {
        __syncthreads();
#pragma unroll
        for (int i = 0; i < 16; ++i) {
            const int r = sr + 4 * i;
            xs[r * 68 + sk] = xr[i];
            ws[r * 64 + sk] = wr[i];
        }
        __syncthreads();
        if (t + 1 < KTILES) {
            const int k0 = (t + 1) * 64;
#pragma unroll
            for (int i = 0; i < 16; ++i) {
                const int r = sr + 4 * i;
                const int gr = R0 + r;
                const int gk = k0 + sk;
                xr[i] = (gr < NN && gk < IN_CH) ? x[(size_t)gr * IN_CH + gk] : 0.f;
                const int wk = k0 + r;
                wr[i] = (wk < IN_CH) ? w0[wk * CC + sk] : 0.f;
            }
        }
#pragma unroll 4
        for (int k4 = 0; k4 < 64; k4 += 4) {
            float4 xv[4], wv[4];
#pragma unroll
            for (int j = 0; j < 4; ++j)
                xv[j] = *(const float4*)&xs[(rg * 4 + j) * 68 + k4];
#pragma unroll
            for (int q = 0; q < 4; ++q)
                wv[q] = *(const float4*)&ws[(k4 + q) * 64 + cg * 4];
#pragma unroll
            for (int j = 0; j < 4; ++j) {
                const float* xf = (const float*)&xv[j];
#pragma unroll
                for (int q = 0; q < 4; ++q) {
                    const float* wf = (const float*)&wv[q];
#pragma unroll
                    for (int i = 0; i < 4; ++i)
                        acc[j][i] = fmaf(xf[q], wf[i], acc[j][i]);
                }
            }
        }
    }

    // ---- GEMM2: elu(h) @ w1 + b1 (single 64-k tile, LDS reuse) ----
    __syncthreads();
#pragma unroll
    for (int j = 0; j < 4; ++j) {
        float4 hv;
        hv.x = eluf(acc[j][0]); hv.y = eluf(acc[j][1]);
        hv.z = eluf(acc[j][2]); hv.w = eluf(acc[j][3]);
        *(float4*)&xs[(rg * 4 + j) * 68 + cg * 4] = hv;
    }
#pragma unroll
    for (int i = 0; i < 16; ++i) {
        const int r = sr + 4 * i;
        ws[r * 64 + sk] = w1[r * CC + sk];
    }
    __syncthreads();

    float acc2[4][4];
    const float4 b1v = *(const float4*)&b1[cg * 4];
#pragma unroll
    for (int j = 0; j < 4; ++j) {
        acc2[j][0] = b1v.x; acc2[j][1] = b1v.y;
        acc2[j][2] = b1v.z; acc2[j][3] = b1v.w;
    }
#pragma unroll 4
    for (int k4 = 0; k4 < 64; k4 += 4) {
        float4 xv[4], wv[4];
#pragma unroll
        for (int j = 0; j < 4; ++j)
            xv[j] = *(const float4*)&xs[(rg * 4 + j) * 68 + k4];
#pragma unroll
        for (int q = 0; q < 4; ++q)
            wv[q] = *(const float4*)&ws[(k4 + q) * 64 + cg * 4];
#pragma unroll
        for (int j = 0; j < 4; ++j) {
            const float* xf = (const float*)&xv[j];
#pragma unroll
            for (int q = 0; q < 4; ++q) {
                const float* wf = (const float*)&wv[q];
#pragma unroll
                for (int i = 0; i < 4; ++i)
                    acc2[j][i] = fmaf(xf[q], wf[i], acc2[j][i]);
            }
        }
    }

    // ---- epilogue: write h2 to LDS, then wave-per-row hop attention ----
    __syncthreads();   // done reading ws (w1)
#pragma unroll
    for (int j = 0; j < 4; ++j)
        *(float4*)&ws[(rg * 4 + j) * 64 + cg * 4] =
            make_float4(acc2[j][0], acc2[j][1], acc2[j][2], acc2[j][3]);
    __syncthreads();

    const int c = tid & 63;
    const int wv4 = tid >> 6;
    const float ha = hop_att0[c];
    const float hb = hop_bias0[0];
#pragma unroll
    for (int rr = 0; rr < 16; ++rr) {
        const int r = wv4 + 4 * rr;
        const float v = ws[r * 64 + c];
        const float attn = wave_sum(ha * eluf(v)) + hb;
        const int row = R0 + r;
        if (row < NN) {
            xout[row * CC + c] = v;
            zout[row * CC + c] = v * attn;
        }
    }
}

// ---------------------------------------------------------------------------
// CSR build (dst-sorted): histogram -> exclusive scan -> scatter
// ---------------------------------------------------------------------------
__global__ __launch_bounds__(256) void k_hist(const int* __restrict__ ei,
                                              int* __restrict__ deg)
{
    const int e = blockIdx.x * 256 + threadIdx.x;   // grid == EE/256
    atomicAdd(&deg[ei[EE + e]], 1);
}

__global__ __launch_bounds__(256) void k_scan(const int* __restrict__ deg,
                                              int* __restrict__ offs)
{
    __shared__ int part[256];
    const int tid = threadIdx.x;
    const int start = tid * 40;
    const int end = start + 40 < NN ? start + 40 : NN;
    int sum = 0;
    for (int i = start; i < end; ++i) sum += deg[i];
    part[tid] = sum;
    __syncthreads();
    if (tid == 0) {
        int run = 0;
        for (int i = 0; i < 256; ++i) { int t = part[i]; part[i] = run; run += t; }
    }
    __syncthreads();
    int run = part[tid];
    for (int i = start; i < end; ++i) { offs[i] = run; run += deg[i]; }
}

__global__ __launch_bounds__(256) void k_scatter(
    const int* __restrict__ ei, const int* __restrict__ offs,
    int* __restrict__ cursor, int* __restrict__ csr_src,
    int* __restrict__ edge_pos)
{
    const int e = blockIdx.x * 256 + threadIdx.x;
    const int d = ei[EE + e];
    const int pos = offs[d] + atomicAdd(&cursor[d], 1);
    csr_src[pos] = ei[e];
    edge_pos[e] = pos;
}

// ---------------------------------------------------------------------------
// Edge attention: 16 lanes per edge (4 edges/wave).
// ---------------------------------------------------------------------------
__global__ __launch_bounds__(256) void k_edge_att(
    const int* __restrict__ ei, const int* __restrict__ edge_pos,
    const float* __restrict__ z, const float* __restrict__ conv_att,
    float scale, float* __restrict__ a_csr, float* __restrict__ adj)
{
    __shared__ float sca[CC];
    if (threadIdx.x < CC) sca[threadIdx.x] = conv_att[threadIdx.x];
    __syncthreads();

    const int e = blockIdx.x * 16 + (threadIdx.x >> 4);   // grid == EE/16
    const int l = threadIdx.x & 15;
    const int s = ei[e];
    const int d = ei[EE + e];
    const float4 zs = *(const float4*)(z + s * CC + l * 4);
    const float4 zd = *(const float4*)(z + d * CC + l * 4);
    float p = sca[4 * l + 0] * eluf((zs.x + zd.x) * scale);
    p = fmaf(sca[4 * l + 1], eluf((zs.y + zd.y) * scale), p);
    p = fmaf(sca[4 * l + 2], eluf((zs.z + zd.z) * scale), p);
    p = fmaf(sca[4 * l + 3], eluf((zs.w + zd.w) * scale), p);
#pragma unroll
    for (int off = 8; off > 0; off >>= 1) p += __shfl_xor(p, off, 64);
    if (l == 0) {
        const float ae = softplusf(p) + 1e-6f;
        a_csr[edge_pos[e]] = ae;
        atomicAdd(&adj[d], ae);
    }
}

// ---------------------------------------------------------------------------
// Fused message gather + UpdateZ. One wave per dst node, lane = channel.
// Metadata broadcast via v_readlane (VALU) -> SGPR base for the row gather;
// manual 4x unroll keeps 4 independent loads in flight. No LDS-pipe traffic.
// ---------------------------------------------------------------------------
__global__ __launch_bounds__(256) void k_msg_fused(
    const int* __restrict__ offs, const int* __restrict__ deg,
    const int* __restrict__ csr_src, const float* __restrict__ a_csr,
    const float* __restrict__ adj, const float* __restrict__ x,
    float* __restrict__ xn, float* __restrict__ z,
    const float* __restrict__ hop_att, const float* __restrict__ hop_bias,
    float scale)
{
    const int n = __builtin_amdgcn_readfirstlane(
        blockIdx.x * 4 + (threadIdx.x >> 6));            // grid == NN/4
    const int c = threadIdx.x & 63;
    const int start = offs[n];
    const int len = deg[n];
    const float invd = rsqrtf(fmaxf(adj[n], 1e-32f));

    float acc = 0.f;
    for (int base = 0; base < len; base += 64) {
        const int cnt = (len - base) < 64 ? (len - base) : 64;
        int s_l = 0; float na_l = 0.f;
        if (c < cnt) {
            s_l = csr_src[start + base + c];
            na_l = a_csr[start + base + c] *
                   rsqrtf(fmaxf(adj[s_l], 1e-32f)) * invd;
        }
        int j = 0;
        for (; j + 4 <= cnt; j += 4) {
            const int s0 = __builtin_amdgcn_readlane(s_l, j);
            const int s1 = __builtin_amdgcn_readlane(s_l, j + 1);
            const int s2 = __builtin_amdgcn_readlane(s_l, j + 2);
            const int s3 = __builtin_amdgcn_readlane(s_l, j + 3);
            const float n0 = __int_as_float(__builtin_amdgcn_readlane(__float_as_int(na_l), j));
            const float n1 = __int_as_float(__builtin_amdgcn_readlane(__float_as_int(na_l), j + 1));
            const float n2 = __int_as_float(__builtin_amdgcn_readlane(__float_as_int(na_l), j + 2));
            const float n3 = __int_as_float(__builtin_amdgcn_readlane(__float_as_int(na_l), j + 3));
            const float v0 = x[s0 * CC + c];
            const float v1 = x[s1 * CC + c];
            const float v2 = x[s2 * CC + c];
            const float v3 = x[s3 * CC + c];
            acc = fmaf(v0, n0, acc);
            acc = fmaf(v1, n1, acc);
            acc = fmaf(v2, n2, acc);
            acc = fmaf(v3, n3, acc);
        }
        for (; j < cnt; ++j) {
            const int s = __builtin_amdgcn_readlane(s_l, j);
            const float na = __int_as_float(__builtin_amdgcn_readlane(__float_as_int(na_l), j));
            acc = fmaf(x[s * CC + c], na, acc);
        }
    }

    // UpdateZ (k >= 1)
    const float zv = z[n * CC + c];
    float g = hop_att[c] * eluf(acc) + hop_att[CC + c] * eluf(zv * scale);
    const float attn = wave_sum(g) + hop_bias[0];
    z[n * CC + c] = zv + acc * attn;
    xn[n * CC + c] = acc;
}

// ---------------------------------------------------------------------------
// Readout
// ---------------------------------------------------------------------------
__global__ __launch_bounds__(256) void k_pool(
    const float* __restrict__ z, const int* __restrict__ batch,
    float* __restrict__ pool, float* __restrict__ cnt)
{
    const int idx = blockIdx.x * 256 + threadIdx.x;  // NN*64 threads
    const int n = idx >> 6;
    const int c = idx & 63;
    const float v = eluf(z[idx]);
    const int b = batch[n];
    atomicAdd(&pool[b * CC + c], v);
    if (c == 0) atomicAdd(&cnt[b], 1.0f);
}

__global__ __launch_bounds__(64) void k_head(
    const float* __restrict__ pool, const float* __restrict__ cnt,
    const float* __restrict__ w_head, const float* __restrict__ b_head,
    float* __restrict__ out)
{
    const int g = threadIdx.x;
    float acc = 0.f;
#pragma unroll 8
    for (int c = 0; c < CC; ++c)
        acc = fmaf(pool[g * CC + c], w_head[c], acc);
    out[g] = acc / fmaxf(cnt[g], 1.0f) + b_head[0];
}

extern "C" void kernel_launch(void* const* d_in, const int* in_sizes, int n_in,
                              void* d_out, int out_size, void* d_ws, size_t ws_size,
                              hipStream_t stream) {
    const float* x        = (const float*)d_in[0];
    const int*   ei       = (const int*)d_in[1];
    const int*   batch    = (const int*)d_in[2];
    const float* w0       = (const float*)d_in[3];
    const float* b0       = (const float*)d_in[4];
    const float* w1       = (const float*)d_in[5];
    const float* b1       = (const float*)d_in[6];
    const float* conv_att = (const float*)d_in[7];
    const float* hop_att0 = (const float*)d_in[8];
    const float* hop_bias0= (const float*)d_in[9];
    const float* hop_att  = (const float*)d_in[10];
    const float* hop_bias = (const float*)d_in[11];
    const float* w_head   = (const float*)d_in[12];
    const float* b_head   = (const float*)d_in[13];
    float* out = (float*)d_out;

    // ---- workspace layout ----
    float* xA    = (float*)d_ws;                 // NN*CC
    float* xB    = xA + NN * CC;                 // NN*CC
    float* zbuf  = xB + NN * CC;                 // NN*CC
    float* a_csr = zbuf + NN * CC;               // EE
    // zero block starts here:
    float* adj9  = a_csr + EE;                   // NLAYER*NN
    float* pool  = adj9 + NLAYER * NN;           // GG*CC
    float* cnt   = pool + GG * CC;               // GG
    int*   deg   = (int*)(cnt + GG);             // NN
    int*   cursor= deg + NN;                     // NN
    // end zero block
    int*   offs  = cursor + NN;                  // NN
    int*   csr_src = offs + NN;                  // EE
    int*   edge_pos = csr_src + EE;              // EE

    const size_t zero_bytes =
        (size_t)(NLAYER * NN + GG * CC + GG + NN + NN) * 4;
    hipMemsetAsync(adj9, 0, zero_bytes, stream);

    k_init<<<(NN + 63) / 64, 256, 0, stream>>>(x, w0, b0, w1, b1,
                                               hop_att0, hop_bias0, xA, zbuf);
    k_hist<<<EE / 256, 256, 0, stream>>>(ei, deg);
    k_scan<<<1, 256, 0, stream>>>(deg, offs);
    k_scatter<<<EE / 256, 256, 0, stream>>>(ei, offs, cursor, csr_src, edge_pos);

    float* xcur = xA;
    float* xnext = xB;
    for (int i = 0; i < NLAYER; ++i) {
        const int k = i + 1;
        const float scale = (float)log(1.0 / (double)k + 1.0 + 1e-6);
        float* adj = adj9 + i * NN;
        k_edge_att<<<EE / 16, 256, 0, stream>>>(ei, edge_pos, zbuf,
                                                conv_att + i * CC, scale,
                                                a_csr, adj);
        k_msg_fused<<<NN / 4, 256, 0, stream>>>(offs, deg, csr_src, a_csr, adj,
                                                xcur, xnext, zbuf,
                                                hop_att + i * 2 * CC,
                                                hop_bias + i, scale);
        float* t = xcur; xcur = xnext; xnext = t;
    }

    k_pool<<<NN * CC / 256, 256, 0, stream>>>(zbuf, batch, pool, cnt);
    k_head<<<1, 64, 0, stream>>>(pool, cnt, w_head, b_head, out);
}